// Round 7
// baseline (133.127 us; speedup 1.0000x reference)
//
#include <hip/hip_runtime.h>
#include <hip/hip_bf16.h>

#define NROWS 8192
#define DDIM  256
#define INV_TEMP 20.0f   // 1/0.05

typedef __attribute__((ext_vector_type(8))) short bf16x8;
typedef __attribute__((ext_vector_type(4))) float f32x4;

// async global->LDS, 16B per lane. LDS dest = uniform base + lane*16.
__device__ static inline void async16(const void* g, void* l) {
    __builtin_amdgcn_global_load_lds(
        (const __attribute__((address_space(1))) void*)g,
        (__attribute__((address_space(3))) void*)l, 16, 0, 0);
}

// ---------------------------------------------------------------------------
// Kernel 1: per-row L2-normalize q and p (fp32), emit bf16 copies (linear
// row-major), fp32 diag. One wave per row, 4 rows per block. Block 0 zeroes
// the rowsum ticket (stream-ordered before kernel 3; graph-replay safe).
// ---------------------------------------------------------------------------
__global__ __launch_bounds__(256) void norm_diag_kernel(
    const float* __restrict__ q, const float* __restrict__ p,
    unsigned short* __restrict__ qn, unsigned short* __restrict__ pn,
    float* __restrict__ diag, int* __restrict__ tickets)
{
    if (blockIdx.x == 0 && threadIdx.x == 0) tickets[0] = 0;

    const int row  = (blockIdx.x << 2) + (threadIdx.x >> 6);
    const int lane = threadIdx.x & 63;

    const float4 qv = ((const float4*)(q + (size_t)row * DDIM))[lane];
    const float4 pv = ((const float4*)(p + (size_t)row * DDIM))[lane];

    float sq = qv.x*qv.x + qv.y*qv.y + qv.z*qv.z + qv.w*qv.w;
    float sp = pv.x*pv.x + pv.y*pv.y + pv.z*pv.z + pv.w*pv.w;
    #pragma unroll
    for (int m = 1; m < 64; m <<= 1) {
        sq += __shfl_xor(sq, m);
        sp += __shfl_xor(sp, m);
    }
    const float qs = 1.0f / fmaxf(sqrtf(sq), 1e-8f);
    const float ps = 1.0f / fmaxf(sqrtf(sp), 1e-8f);

    const float qx = qv.x*qs, qy = qv.y*qs, qz = qv.z*qs, qw = qv.w*qs;
    const float px = pv.x*ps, py = pv.y*ps, pz = pv.z*ps, pw = pv.w*ps;

    float d = qx*px + qy*py + qz*pz + qw*pw;
    #pragma unroll
    for (int m = 1; m < 64; m <<= 1) d += __shfl_xor(d, m);
    if (lane == 0) diag[row] = d * INV_TEMP;

    union { unsigned short u16[4]; uint2 v; } uq, up;
    {
        __hip_bfloat16 b;
        b = __float2bfloat16(qx); uq.u16[0] = *(unsigned short*)&b;
        b = __float2bfloat16(qy); uq.u16[1] = *(unsigned short*)&b;
        b = __float2bfloat16(qz); uq.u16[2] = *(unsigned short*)&b;
        b = __float2bfloat16(qw); uq.u16[3] = *(unsigned short*)&b;
        b = __float2bfloat16(px); up.u16[0] = *(unsigned short*)&b;
        b = __float2bfloat16(py); up.u16[1] = *(unsigned short*)&b;
        b = __float2bfloat16(pz); up.u16[2] = *(unsigned short*)&b;
        b = __float2bfloat16(pw); up.u16[3] = *(unsigned short*)&b;
    }
    *(uint2*)(qn + (size_t)row * DDIM + lane * 4) = uq.v;
    *(uint2*)(pn + (size_t)row * DDIM + lane * 4) = up.v;
}

// ---------------------------------------------------------------------------
// Kernel 2: fused GEMM + sum-exp, 8-PHASE schedule (T3+T4+T5 port of m201).
// 256x256 tile, 512 threads = 8 waves (2 row x 4 col), wave tile 128x64.
// K=256 = 4 K-tiles of BK=64, each split into 2 k-halves (K=32 per phase).
// LDS = 2 K-tile buffers x (A 32K | B 32K) = 128 KB; each buffer has 2
// independently-tracked halves -> staging runs 2 K-tiles ahead, loads stay
// in flight across every barrier (counted vmcnt, never drained mid-loop).
//
// Per phase: {12 ds_read_b128 of current half || issue 4 async16 for half
// two-K-tiles ahead} -> vmcnt(N per ledger) -> lgkmcnt(0) (race guard: this
// wave's ds_reads complete before it signals) -> s_barrier -> setprio(1)
// 32 MFMA setprio(0). Next phase's ds_reads overlap this phase's MFMAs.
//
// vmcnt ledger (4 loads/stage-event, per-wave, issue order
// (0,0)(0,1)(1,0)(1,1)(2,0)(2,1)(3,0)(3,1)): prologue 8; P1-P5 8; P6 4;
// P7 0; P8 none. Slot-overwrite safety: stage(kt+2,h) writes the slot whose
// reads completed at phase(kt,h)'s lgkmcnt(0)+barrier, >=1 phase earlier.
// LDS chunk layout per (tile,half): 1KB [quad][l16][16B] -> lane*16 linear
// (matches async16 dest rule), ds_read_b128 conflict-free (measured 0).
// ---------------------------------------------------------------------------
__global__ __launch_bounds__(512, 2) void simexp_kernel(
    const unsigned short* __restrict__ qn,
    const unsigned short* __restrict__ pn,
    float* __restrict__ part)       // [32 colblocks][8192 rows]
{
    __shared__ unsigned char lds[131072];  // 2 x (A 32K | B 32K)

    const int tid  = threadIdx.x;
    const int lane = tid & 63;
    const int w    = tid >> 6;        // wave 0..7
    const int wr   = w >> 2;          // wave row (0..1): 128 rows
    const int wc   = w & 3;           // wave col (0..3): 64 cols
    const int quad = lane >> 4;
    const int l16  = lane & 15;
    const int qoff = lane * 16;       // = quad*256 + l16*16

    // ---- XCD-chunked swizzle (bijective on 1024 blocks) ----
    const int L   = blockIdx.y * 32 + blockIdx.x;
    const int xcd = L & 7;
    const int c   = L >> 3;
    const int rowblk = xcd * 4 + (c & 3);
    const int colblk = c >> 2;
    const int rowbase = rowblk * 256;
    const int colbase = colblk * 256;

    // staging sources: wave w owns 16-row tiles {2w, 2w+1} of A and B.
    // lane l -> row (l&15), 16B chunk (l>>4). K offset added per stage.
    const unsigned short* gA0 = qn + (size_t)(rowbase + (2*w  )*16 + l16) * DDIM + quad * 8;
    const unsigned short* gA1 = qn + (size_t)(rowbase + (2*w+1)*16 + l16) * DDIM + quad * 8;
    const unsigned short* gB0 = pn + (size_t)(colbase + (2*w  )*16 + l16) * DDIM + quad * 8;
    const unsigned short* gB1 = pn + (size_t)(colbase + (2*w+1)*16 + l16) * DDIM + quad * 8;

    f32x4 acc[8][4];
    #pragma unroll
    for (int i = 0; i < 8; ++i)
        #pragma unroll
        for (int j = 0; j < 4; ++j) acc[i][j] = (f32x4)0.0f;

    // stage half (SKT, SPH): 4 async16 per wave (A tiles 2w,2w+1; B same).
#define STG(SKT, SPH) do {                                              \
        unsigned char* _d = lds + ((SKT) & 1) * 65536 + (SPH) * 1024;   \
        const int _ko = (SKT) * 64 + (SPH) * 32;                        \
        async16(gA0 + _ko, _d +         (2*w    ) * 2048);              \
        async16(gA1 + _ko, _d +         (2*w + 1) * 2048);              \
        async16(gB0 + _ko, _d + 32768 + (2*w    ) * 2048);              \
        async16(gB1 + _ko, _d + 32768 + (2*w + 1) * 2048);              \
    } while (0)

#define MFMA_CLUSTER() do {                                             \
        __builtin_amdgcn_s_setprio(1);                                  \
        _Pragma("unroll")                                               \
        for (int i = 0; i < 8; ++i)                                     \
            _Pragma("unroll")                                           \
            for (int j = 0; j < 4; ++j)                                 \
                acc[i][j] = __builtin_amdgcn_mfma_f32_16x16x32_bf16(    \
                    af[i], bf[j], acc[i][j], 0, 0, 0);                  \
        __builtin_amdgcn_s_setprio(0);                                  \
    } while (0)

    // phase: read half (BUF,PH), optional stage, counted waits, barrier, MFMA
#define PHASE(BUF, PH, STGSTMT, VMSTR) {                                \
        bf16x8 af[8], bf[4];                                            \
        const unsigned char* _ba = lds + (BUF) * 65536 + (PH) * 1024;   \
        _Pragma("unroll")                                               \
        for (int i = 0; i < 8; ++i)                                     \
            af[i] = *(const bf16x8*)(_ba + (wr*8 + i) * 2048 + qoff);   \
        _Pragma("unroll")                                               \
        for (int j = 0; j < 4; ++j)                                     \
            bf[j] = *(const bf16x8*)(_ba + 32768 + (wc*4 + j) * 2048 + qoff); \
        STGSTMT;                                                        \
        asm volatile(VMSTR ::: "memory");                               \
        asm volatile("s_waitcnt lgkmcnt(0)" ::: "memory");              \
        __builtin_amdgcn_s_barrier();                                   \
        asm volatile("" ::: "memory");                                  \
        MFMA_CLUSTER();                                                 \
    }

    // prologue: 3 halves in flight, wait first
    STG(0, 0); STG(0, 1); STG(1, 0);
    asm volatile("s_waitcnt vmcnt(8)" ::: "memory");
    __builtin_amdgcn_s_barrier();
    asm volatile("" ::: "memory");

    PHASE(0, 0, STG(1, 1), "s_waitcnt vmcnt(8)")   // P1: compute (0,0)
    PHASE(0, 1, STG(2, 0), "s_waitcnt vmcnt(8)")   // P2: (0,1)
    PHASE(1, 0, STG(2, 1), "s_waitcnt vmcnt(8)")   // P3: (1,0)
    PHASE(1, 1, STG(3, 0), "s_waitcnt vmcnt(8)")   // P4: (1,1)
    PHASE(0, 0, STG(3, 1), "s_waitcnt vmcnt(8)")   // P5: (2,0)
    PHASE(0, 1, ((void)0),  "s_waitcnt vmcnt(4)")  // P6: (2,1)
    PHASE(1, 0, ((void)0),  "s_waitcnt vmcnt(0)")  // P7: (3,0)
    {   // P8: (3,1) — nothing outstanding, no sync needed
        bf16x8 af[8], bf[4];
        const unsigned char* _ba = lds + 65536 + 1024;
        #pragma unroll
        for (int i = 0; i < 8; ++i)
            af[i] = *(const bf16x8*)(_ba + (wr*8 + i) * 2048 + qoff);
        #pragma unroll
        for (int j = 0; j < 4; ++j)
            bf[j] = *(const bf16x8*)(_ba + 32768 + (wc*4 + j) * 2048 + qoff);
        MFMA_CLUSTER();
    }
#undef PHASE
#undef MFMA_CLUSTER
#undef STG

    // epilogue ------------------------------------------------------------
    __syncthreads();                   // all LDS reads done; reuse LDS
    float* red = (float*)lds;          // 4 x 256 floats: [wc][256 rows]

    #pragma unroll
    for (int i = 0; i < 8; ++i)
        #pragma unroll
        for (int r = 0; r < 4; ++r) {
            float s = __expf(acc[i][0][r] * INV_TEMP)
                    + __expf(acc[i][1][r] * INV_TEMP)
                    + __expf(acc[i][2][r] * INV_TEMP)
                    + __expf(acc[i][3][r] * INV_TEMP);
            s += __shfl_xor(s, 1);
            s += __shfl_xor(s, 2);
            s += __shfl_xor(s, 4);
            s += __shfl_xor(s, 8);
            if (l16 == 0)
                red[wc * 256 + wr * 128 + i * 16 + quad * 4 + r] = s;
        }
    __syncthreads();

    if (tid < 256)
        part[(size_t)colblk * NROWS + rowbase + tid] =
            red[tid] + red[256 + tid] + red[512 + tid] + red[768 + tid];
}

// ---------------------------------------------------------------------------
// Kernel 3: per-row total + log - diag, block partials, fused final mean via
// a 64-block completion ticket (64 agent-scope RMWs, ~us-scale).
// ---------------------------------------------------------------------------
__global__ __launch_bounds__(128) void rowsum_final_kernel(
    const float* __restrict__ part, const float* __restrict__ diag,
    float* __restrict__ loss_part, int* __restrict__ tickets,
    float* __restrict__ out)
{
    const int row = blockIdx.x * 128 + threadIdx.x;
    float s = 0.0f;
    #pragma unroll 4
    for (int cb = 0; cb < 32; ++cb)
        s += part[(size_t)cb * NROWS + row];     // coalesced across threads
    float v = logf(s) - diag[row];

    #pragma unroll
    for (int m = 1; m < 64; m <<= 1) v += __shfl_xor(v, m);
    __shared__ float wsum[2];
    __shared__ int swin;
    if ((threadIdx.x & 63) == 0) wsum[threadIdx.x >> 6] = v;
    __syncthreads();
    if (threadIdx.x == 0) {
        __hip_atomic_store(&loss_part[blockIdx.x], wsum[0] + wsum[1],
            __ATOMIC_RELEASE, __HIP_MEMORY_SCOPE_AGENT);
        swin = __hip_atomic_fetch_add(&tickets[0], 1,
                   __ATOMIC_ACQ_REL, __HIP_MEMORY_SCOPE_AGENT);
    }
    __syncthreads();
    if (swin != 63) return;            // not the last block

    if (threadIdx.x < 64) {
        float x = __hip_atomic_load(&loss_part[threadIdx.x],
                      __ATOMIC_RELAXED, __HIP_MEMORY_SCOPE_AGENT);
        #pragma unroll
        for (int m = 1; m < 64; m <<= 1) x += __shfl_xor(x, m);
        if (threadIdx.x == 0) out[0] = x * (1.0f / NROWS);
    }
}

// ---------------------------------------------------------------------------
extern "C" void kernel_launch(void* const* d_in, const int* in_sizes, int n_in,
                              void* d_out, int out_size, void* d_ws, size_t ws_size,
                              hipStream_t stream)
{
    const float* q = (const float*)d_in[0];
    const float* p = (const float*)d_in[1];

    char* ws = (char*)d_ws;
    unsigned short* qn   = (unsigned short*)ws;                          // 4 MB
    unsigned short* pn   = (unsigned short*)(ws + (size_t)NROWS*DDIM*2); // 4 MB
    float* part      = (float*)(ws + 2*(size_t)NROWS*DDIM*2);            // 1 MB
    float* diag      = part + 32 * (size_t)NROWS;                        // 32 KB
    float* loss_part = diag + NROWS;                                     // 256 B
    int*   tickets   = (int*)(loss_part + 64);

    norm_diag_kernel<<<NROWS/4, 256, 0, stream>>>(q, p, qn, pn, diag, tickets);

    dim3 grid(32, 32);   // colblocks x rowblocks (remapped in-kernel)
    simexp_kernel<<<grid, 512, 0, stream>>>(qn, pn, part);

    rowsum_final_kernel<<<64, 128, 0, stream>>>(part, diag, loss_part,
                                                tickets, (float*)d_out);
}